// Round 1
// baseline (268.632 us; speedup 1.0000x reference)
//
#include <hip/hip_runtime.h>

#define BATCH 256
#define NIN   1152
#define NOUT  10
#define DDIM  16
#define KPT   18   // NIN / 64 capsules per thread (each thread owns a d-quad)

// R4: oo-pair fusion. One block per (batch, oo-pair p), 512 threads.
// Half h = t>>8 runs out-capsule oo = 2p+h with the exact R3 compute structure
// (proven replay-stable). Rationale: a 640B capsule record spans 5 x 128B
// lines; oo=2p and 2p+1 share line p exactly. Fusing the pair into one block
// guarantees both 64B halves of every fetched 128B line are consumed in the
// same load burst (L2-resident), independent of cross-block dispatch timing.
// Also: squash scale is deferred (applied at use sites) -> 2 fewer barriers
// per iteration, numerically identical (same single rounding of vsh*scale).
__global__ __launch_bounds__(512, 4)
void routing_kernel(const float* __restrict__ u_hat, float* __restrict__ out) {
    __shared__ float bsh[2][NIN];     // routing logits b_i, per half
    __shared__ float wsh[2][NIN];     // exp(b_i - m), per half
    __shared__ float red[8][DDIM];    // per-wave partial s (waves 0-3 h0, 4-7 h1)
    __shared__ float vsh[2][DDIM];    // raw s/Z (squash scale applied at use)
    __shared__ float smax[8];         // per-wave max
    __shared__ float ssum[8];         // per-wave sum

    const int t    = threadIdx.x;
    const int h    = t >> 8;          // half: which oo of the pair
    const int tt   = t & 255;
    const int q    = tt & 3;          // d-quad owner
    const int g    = tt >> 2;         // capsule group
    const int wave = t >> 6;          // 0..7
    const int lane = t & 63;

    // XCD-aware decode: 1280 blocks = 8 XCDs x 32 bb x 5 pairs (bijective)
    const int x   = blockIdx.x;
    const int xcd = x & 7;
    const int j   = x >> 3;           // 0..159
    const int p   = j % 5;            // oo-pair
    const int bb  = xcd * 32 + j / 5;
    const int oo  = 2 * p + h;

    // u_hat flat index: ((bb*NIN + i)*NOUT + oo)*DDIM + d
    const float* base = u_hat + (size_t)bb * (NIN * NOUT * DDIM) + oo * DDIM + q * 4;

    float4 u[KPT];
#pragma unroll
    for (int k = 0; k < KPT; ++k) {
        const int i = g + 64 * k;
        u[k] = *reinterpret_cast<const float4*>(base + (size_t)i * (NOUT * DDIM));
    }

    for (int i = tt; i < NIN; i += 256) bsh[h][i] = 0.0f;
    __syncthreads();

    float scale = 0.0f;               // squash scale, live after the loop
    for (int r = 0; r < 3; ++r) {
        // ---- softmax over n_in: max (per half) ----
        float m = -3.4e38f;
        for (int i = tt; i < NIN; i += 256) m = fmaxf(m, bsh[h][i]);
        for (int off = 32; off >= 1; off >>= 1) m = fmaxf(m, __shfl_down(m, off));
        if (lane == 0) smax[wave] = m;
        __syncthreads();
        m = fmaxf(fmaxf(smax[h * 4 + 0], smax[h * 4 + 1]),
                  fmaxf(smax[h * 4 + 2], smax[h * 4 + 3]));

        // ---- w = exp(b - m), Z = sum w (per half) ----
        float z = 0.0f;
        for (int i = tt; i < NIN; i += 256) {
            const float w = __expf(bsh[h][i] - m);
            wsh[h][i] = w;
            z += w;
        }
        for (int off = 32; off >= 1; off >>= 1) z += __shfl_down(z, off);
        if (lane == 0) ssum[wave] = z;
        __syncthreads();
        const float invZ = 1.0f / (ssum[h * 4 + 0] + ssum[h * 4 + 1] +
                                   ssum[h * 4 + 2] + ssum[h * 4 + 3]);

        // ---- s_d = (1/Z) * sum_i w_i * u[i][d] ----
        float sx = 0.f, sy = 0.f, sz = 0.f, sw = 0.f;
#pragma unroll
        for (int k = 0; k < KPT; ++k) {
            const float w = wsh[h][g + 64 * k];
            sx += w * u[k].x; sy += w * u[k].y; sz += w * u[k].z; sw += w * u[k].w;
        }
        // reduce across the 16 groups of this wave (strides multiple of 4 keep q fixed)
        for (int off = 32; off >= 4; off >>= 1) {
            sx += __shfl_down(sx, off);
            sy += __shfl_down(sy, off);
            sz += __shfl_down(sz, off);
            sw += __shfl_down(sw, off);
        }
        if (lane < 4) {
            float* rp = &red[wave][lane * 4];
            rp[0] = sx; rp[1] = sy; rp[2] = sz; rp[3] = sw;
        }
        __syncthreads();
        if (tt < DDIM) {
            vsh[h][tt] = (red[h * 4 + 0][tt] + red[h * 4 + 1][tt] +
                          red[h * 4 + 2][tt] + red[h * 4 + 3][tt]) * invZ;
        }
        __syncthreads();

        // ---- squash scale (redundant per-thread scalar math, broadcast reads);
        //      scale is NOT written back to LDS -> saves 2 barriers/iter ----
        float sqr = 0.0f;
#pragma unroll
        for (int d = 0; d < DDIM; ++d) { const float sv = vsh[h][d]; sqr += sv * sv; }
        scale = sqr / ((1.0f + sqr) * sqrtf(sqr + 1e-7f));

        if (r == 2) break;

        // ---- agreement a_i = sum_d u[i][d]*v_d ; b_i += a_i ----
        const float vx = vsh[h][q * 4 + 0] * scale, vy = vsh[h][q * 4 + 1] * scale;
        const float vz = vsh[h][q * 4 + 2] * scale, vw = vsh[h][q * 4 + 3] * scale;
#pragma unroll
        for (int k = 0; k < KPT; ++k) {
            float a = u[k].x * vx + u[k].y * vy + u[k].z * vz + u[k].w * vw;
            a += __shfl_xor(a, 1);
            a += __shfl_xor(a, 2);
            if (q == 0) bsh[h][g + 64 * k] += a;
        }
        __syncthreads();
    }

    if (tt < DDIM) {
        out[(size_t)(bb * NOUT + oo) * DDIM + tt] = vsh[h][tt] * scale;
    }
}

extern "C" void kernel_launch(void* const* d_in, const int* in_sizes, int n_in,
                              void* d_out, int out_size, void* d_ws, size_t ws_size,
                              hipStream_t stream) {
    const float* u_hat = (const float*)d_in[0];
    float* out = (float*)d_out;
    routing_kernel<<<dim3(BATCH * NOUT / 2), dim3(512), 0, stream>>>(u_hat, out);
}

// Round 2
// 262.075 us; speedup vs baseline: 1.0250x; 1.0250x over previous
//
#include <hip/hip_runtime.h>

#define BATCH 256
#define NIN   1152
#define NOUT  10
#define DDIM  16
#define KPT   9    // NIN / 128 capsules per thread (each thread owns a d-quad)

// R5: occupancy push. Pair-fusion (R4) was proven neutral -> L2 already merges
// sibling half-lines; reverted to one block per (batch, out_capsule), but with
// 512 threads and KPT=9 (u-array 36 VGPRs instead of 72). Target: ~60 VGPRs
// -> 6-8 waves/SIMD -> 3-4 co-resident blocks/CU (vs 2 before), so block n+1's
// HBM loads hide block n's barrier-heavy compute. Phase structure = R3's
// proven-replay-stable one (no r=0 skip, no warm-LDS), plus R4's deferred
// squash scale (numerically identical, 2 fewer barriers/iter, passed R4).
// Thread t: q = t&3 owns d in [4q,4q+4); g = t>>2 in [0,128) owns i = g+128k.
__global__ __launch_bounds__(512, 6)
void routing_kernel(const float* __restrict__ u_hat, float* __restrict__ out) {
    __shared__ float bsh[NIN];        // routing logits b_i
    __shared__ float wsh[NIN];        // exp(b_i - m)
    __shared__ float red[8][DDIM];    // per-wave partial s
    __shared__ float vsh[DDIM];       // raw s/Z (squash scale applied at use)
    __shared__ float smax[8];         // per-wave max
    __shared__ float ssum[8];         // per-wave sum

    const int t    = threadIdx.x;
    const int q    = t & 3;
    const int g    = t >> 2;          // 0..127
    const int wave = t >> 6;          // 0..7
    const int lane = t & 63;

    // XCD-aware decode: 2560 blocks = 8 XCDs x 32 bb x 10 oo (bijective)
    const int x   = blockIdx.x;
    const int xcd = x & 7;
    const int j   = x >> 3;           // 0..319
    const int oo  = j % NOUT;
    const int bb  = xcd * 32 + j / NOUT;

    // u_hat flat index: ((bb*NIN + i)*NOUT + oo)*DDIM + d
    const float* base = u_hat + (size_t)bb * (NIN * NOUT * DDIM) + oo * DDIM + q * 4;

    float4 u[KPT];
#pragma unroll
    for (int k = 0; k < KPT; ++k) {
        const int i = g + 128 * k;
        u[k] = *reinterpret_cast<const float4*>(base + (size_t)i * (NOUT * DDIM));
    }

    for (int i = t; i < NIN; i += 512) bsh[i] = 0.0f;
    __syncthreads();

    float scale = 0.0f;               // squash scale, live after the loop
    for (int r = 0; r < 3; ++r) {
        // ---- softmax over n_in: max ----
        float m = -3.4e38f;
        for (int i = t; i < NIN; i += 512) m = fmaxf(m, bsh[i]);
        for (int off = 32; off >= 1; off >>= 1) m = fmaxf(m, __shfl_down(m, off));
        if (lane == 0) smax[wave] = m;
        __syncthreads();
        m = fmaxf(fmaxf(fmaxf(smax[0], smax[1]), fmaxf(smax[2], smax[3])),
                  fmaxf(fmaxf(smax[4], smax[5]), fmaxf(smax[6], smax[7])));

        // ---- w = exp(b - m), Z = sum w ----
        float z = 0.0f;
        for (int i = t; i < NIN; i += 512) {
            const float w = __expf(bsh[i] - m);
            wsh[i] = w;
            z += w;
        }
        for (int off = 32; off >= 1; off >>= 1) z += __shfl_down(z, off);
        if (lane == 0) ssum[wave] = z;
        __syncthreads();
        const float invZ = 1.0f / (((ssum[0] + ssum[1]) + (ssum[2] + ssum[3])) +
                                   ((ssum[4] + ssum[5]) + (ssum[6] + ssum[7])));

        // ---- s_d = (1/Z) * sum_i w_i * u[i][d] ----
        float sx = 0.f, sy = 0.f, sz = 0.f, sw = 0.f;
#pragma unroll
        for (int k = 0; k < KPT; ++k) {
            const float w = wsh[g + 128 * k];
            sx += w * u[k].x; sy += w * u[k].y; sz += w * u[k].z; sw += w * u[k].w;
        }
        // reduce across the 16 g-groups of this wave (strides multiple of 4 keep q fixed)
        for (int off = 32; off >= 4; off >>= 1) {
            sx += __shfl_down(sx, off);
            sy += __shfl_down(sy, off);
            sz += __shfl_down(sz, off);
            sw += __shfl_down(sw, off);
        }
        if (lane < 4) {
            float* rp = &red[wave][lane * 4];
            rp[0] = sx; rp[1] = sy; rp[2] = sz; rp[3] = sw;
        }
        __syncthreads();
        if (t < DDIM) {
            vsh[t] = (((red[0][t] + red[1][t]) + (red[2][t] + red[3][t])) +
                      ((red[4][t] + red[5][t]) + (red[6][t] + red[7][t]))) * invZ;
        }
        __syncthreads();

        // ---- squash scale (redundant per-thread scalar math, broadcast reads);
        //      scale is NOT written back to LDS -> deferred to use sites ----
        float sqr = 0.0f;
#pragma unroll
        for (int d = 0; d < DDIM; ++d) { const float sv = vsh[d]; sqr += sv * sv; }
        scale = sqr / ((1.0f + sqr) * sqrtf(sqr + 1e-7f));

        if (r == 2) break;

        // ---- agreement a_i = sum_d u[i][d]*v_d ; b_i += a_i ----
        const float vx = vsh[q * 4 + 0] * scale, vy = vsh[q * 4 + 1] * scale;
        const float vz = vsh[q * 4 + 2] * scale, vw = vsh[q * 4 + 3] * scale;
#pragma unroll
        for (int k = 0; k < KPT; ++k) {
            float a = u[k].x * vx + u[k].y * vy + u[k].z * vz + u[k].w * vw;
            a += __shfl_xor(a, 1);
            a += __shfl_xor(a, 2);
            if (q == 0) bsh[g + 128 * k] += a;
        }
        __syncthreads();
    }

    if (t < DDIM) {
        out[(size_t)(bb * NOUT + oo) * DDIM + t] = vsh[t] * scale;
    }
}

extern "C" void kernel_launch(void* const* d_in, const int* in_sizes, int n_in,
                              void* d_out, int out_size, void* d_ws, size_t ws_size,
                              hipStream_t stream) {
    const float* u_hat = (const float*)d_in[0];
    float* out = (float*)d_out;
    routing_kernel<<<dim3(BATCH * NOUT), dim3(512), 0, stream>>>(u_hat, out);
}